// Round 2
// baseline (283.287 us; speedup 1.0000x reference)
//
#include <hip/hip_runtime.h>

// GRU fused kernel for MI355X (gfx950). R2: register-resident W_hh + biases,
// chained MFMAs for r/z gates, packed bf16 relayout, padded LDS for W_ih.
// T=24, N=65536 pixels, F=H=32, gates r,z,n (3H=96).
// One wave = 16 pixels for all 24 steps; gates^T(96x16) = W(96x32) @ x^T/h^T(32x16).

#define TSTEPS 24
#define NPIX 65536
#define PADW 40   // shorts per W_ih row in LDS (80 B) — breaks bank aliasing

typedef __attribute__((ext_vector_type(8))) short bf16x8;
typedef __attribute__((ext_vector_type(4))) float f32x4;
typedef __attribute__((ext_vector_type(4))) unsigned int u32x4;

#define MFMA16(a, b, c) __builtin_amdgcn_mfma_f32_16x16x32_bf16((a), (b), (c), 0, 0, 0)

__device__ __forceinline__ unsigned short f2bf(float f) {
  unsigned u = __builtin_bit_cast(unsigned, f);
  u += 0x7fffu + ((u >> 16) & 1u);   // RNE
  return (unsigned short)(u >> 16);
}

// pack two f32 -> (bf16(a) low | bf16(b) high), RNE, via v_perm
__device__ __forceinline__ unsigned pk2(float a, float b) {
  unsigned ua = __builtin_bit_cast(unsigned, a);
  unsigned ub = __builtin_bit_cast(unsigned, b);
  ua += 0x7fffu + ((ua >> 16) & 1u);
  ub += 0x7fffu + ((ub >> 16) & 1u);
  return __builtin_amdgcn_perm(ub, ua, 0x07060302u);  // {ub.b3,ub.b2,ua.b3,ua.b2}
}

__device__ __forceinline__ bf16x8 pack8(f32x4 a, f32x4 b) {
  u32x4 r = { pk2(a[0], a[1]), pk2(a[2], a[3]), pk2(b[0], b[1]), pk2(b[2], b[3]) };
  return __builtin_bit_cast(bf16x8, r);
}

__device__ __forceinline__ float sigmoid_(float x) {
  return __builtin_amdgcn_rcpf(1.f + __expf(-x));
}
__device__ __forceinline__ float tanh_(float x) {
  return 1.f - 2.f * __builtin_amdgcn_rcpf(__expf(2.f * x) + 1.f);
}

// h (two C-layout f32x4 tiles) -> B-layout bf16x8 fragment, packed shuffle:
// pack row-pairs into dwords first, then 8 shfl + 4 select.
__device__ __forceinline__ bf16x8 relayout_h(const f32x4 h0, const f32x4 h1, int lane) {
  unsigned p00 = pk2(h0[0], h0[1]), p01 = pk2(h0[2], h0[3]);
  unsigned p10 = pk2(h1[0], h1[1]), p11 = pk2(h1[2], h1[3]);
  const int lo = (lane & 15) | ((lane & 16) << 1);   // col + (q&1)*32
  const int hi = lo + 16;
  unsigned a0 = (unsigned)__shfl((int)p00, lo, 64);
  unsigned a1 = (unsigned)__shfl((int)p01, lo, 64);
  unsigned a2 = (unsigned)__shfl((int)p00, hi, 64);
  unsigned a3 = (unsigned)__shfl((int)p01, hi, 64);
  unsigned b0 = (unsigned)__shfl((int)p10, lo, 64);
  unsigned b1 = (unsigned)__shfl((int)p11, lo, 64);
  unsigned b2 = (unsigned)__shfl((int)p10, hi, 64);
  unsigned b3 = (unsigned)__shfl((int)p11, hi, 64);
  const bool t1 = (lane & 32) != 0;                  // q >= 2 -> tile 1
  u32x4 d = { t1 ? b0 : a0, t1 ? b1 : a1, t1 ? b2 : a2, t1 ? b3 : a3 };
  return __builtin_bit_cast(bf16x8, d);
}

__global__ __launch_bounds__(256, 4)
void gru_fused(const float* __restrict__ spatial, const float* __restrict__ met,
               const float* __restrict__ ctx,
               const float* __restrict__ W_ih, const float* __restrict__ W_hh,
               const float* __restrict__ b_ih, const float* __restrict__ b_hh,
               const float* __restrict__ Wout, float* __restrict__ out) {
  __shared__ __align__(16) unsigned short sWih[96 * PADW];

  const int tid = threadIdx.x;
  for (int i = tid; i < 96 * 32; i += 256) {
    int r = i >> 5, c = i & 31;
    sWih[r * PADW + c] = f2bf(W_ih[i]);
  }
  __syncthreads();

  const int lane = tid & 63;
  const int col = lane & 15;     // pixel column
  const int q = lane >> 4;       // k-quad
  const int wave = blockIdx.x * 4 + (tid >> 6);
  const long p = (long)wave * 16 + col;

  // W_hh fragments resident in VGPRs (wave-invariant rows, lane-specific)
  bf16x8 whh[6];
#pragma unroll
  for (int i = 0; i < 6; ++i) {
    const float* wp = W_hh + (i * 16 + col) * 32 + q * 8;
    whh[i] = pack8(*(const f32x4*)wp, *(const f32x4*)(wp + 4));
  }
  // biases as MFMA C-inits (f32, resident)
  f32x4 cS[4];
#pragma unroll
  for (int i = 0; i < 4; ++i)
    cS[i] = *(const f32x4*)&b_ih[i * 16 + q * 4] + *(const f32x4*)&b_hh[i * 16 + q * 4];
  const f32x4 cG4 = *(const f32x4*)&b_ih[64 + q * 4];
  const f32x4 cG5 = *(const f32x4*)&b_ih[80 + q * 4];
  const f32x4 cH4 = *(const f32x4*)&b_hh[64 + q * 4];
  const f32x4 cH5 = *(const f32x4*)&b_hh[80 + q * 4];

  // per-lane x stream: lane provides x^T[k=q*8+j][col]
  const float* xptr;
  long xstride;
  if (q < 2)       { xptr = spatial + p * 16 + q * 8; xstride = (long)NPIX * 16; }
  else if (q == 2) { xptr = met + p * 8;              xstride = (long)NPIX * 8;  }
  else             { xptr = ctx + p * 8;              xstride = (long)NPIX * 8;  }

  bf16x8 bx = pack8(*(const f32x4*)xptr, *(const f32x4*)(xptr + 4));
  xptr += xstride;

  f32x4 h0 = {0.f, 0.f, 0.f, 0.f};
  f32x4 h1 = {0.f, 0.f, 0.f, 0.f};

#pragma unroll 1
  for (int t = 0; t < TSTEPS; ++t) {
    // issue next step's x loads early; pack at end of body
    f32x4 xna, xnb;
    if (t < TSTEPS - 1) {
      xna = *(const f32x4*)xptr;
      xnb = *(const f32x4*)(xptr + 4);
      xptr += xstride;
    }

    bf16x8 bh = relayout_h(h0, h1, lane);

    // W_ih fragments from padded LDS (16B aligned: i*1280 + col*80 + q*16 bytes)
    const int wb = col * PADW + q * 8;
    bf16x8 a0 = *(const bf16x8*)&sWih[wb];
    bf16x8 a1 = *(const bf16x8*)&sWih[wb + 16 * PADW];
    bf16x8 a2 = *(const bf16x8*)&sWih[wb + 32 * PADW];
    bf16x8 a3 = *(const bf16x8*)&sWih[wb + 48 * PADW];
    bf16x8 a4 = *(const bf16x8*)&sWih[wb + 64 * PADW];
    bf16x8 a5 = *(const bf16x8*)&sWih[wb + 80 * PADW];

    // gx (bias in C), then chain gh onto it for r/z tiles
    f32x4 g0 = MFMA16(a0, bx, cS[0]);
    f32x4 g1 = MFMA16(a1, bx, cS[1]);
    f32x4 g2 = MFMA16(a2, bx, cS[2]);
    f32x4 g3 = MFMA16(a3, bx, cS[3]);
    f32x4 G4 = MFMA16(a4, bx, cG4);
    f32x4 G5 = MFMA16(a5, bx, cG5);
    f32x4 S0 = MFMA16(whh[0], bh, g0);
    f32x4 S1 = MFMA16(whh[1], bh, g1);
    f32x4 S2 = MFMA16(whh[2], bh, g2);
    f32x4 S3 = MFMA16(whh[3], bh, g3);
    f32x4 H4 = MFMA16(whh[4], bh, cH4);
    f32x4 H5 = MFMA16(whh[5], bh, cH5);

    // gate math (tiles: S0,S1=r  S2,S3=z  G4/H4,G5/H5=n ; h tiles 0,1)
#pragma unroll
    for (int r = 0; r < 4; ++r) {
      float rv0 = sigmoid_(S0[r]);
      float rv1 = sigmoid_(S1[r]);
      float zv0 = sigmoid_(S2[r]);
      float zv1 = sigmoid_(S3[r]);
      float nv0 = tanh_(G4[r] + rv0 * H4[r]);
      float nv1 = tanh_(G5[r] + rv1 * H5[r]);
      h0[r] = nv0 + zv0 * (h0[r] - nv0);
      h1[r] = nv1 + zv1 * (h1[r] - nv1);
    }

    if (t < TSTEPS - 1) bx = pack8(xna, xnb);
  }

  // epilogue: out^T(16x16) = W^T(16x32) @ h^T(32x16)
  bf16x8 bhf = relayout_h(h0, h1, lane);
  float w[8];
#pragma unroll
  for (int j = 0; j < 8; ++j) w[j] = Wout[(q * 8 + j) * 16 + col];
  u32x4 awp = { pk2(w[0], w[1]), pk2(w[2], w[3]), pk2(w[4], w[5]), pk2(w[6], w[7]) };
  bf16x8 aw = __builtin_bit_cast(bf16x8, awp);
  const f32x4 zero = {0.f, 0.f, 0.f, 0.f};
  f32x4 o = MFMA16(aw, bhf, zero);
  *(f32x4*)&out[p * 16 + q * 4] = o;   // out[p*16 + q*4 .. +3]
}

extern "C" void kernel_launch(void* const* d_in, const int* in_sizes, int n_in,
                              void* d_out, int out_size, void* d_ws, size_t ws_size,
                              hipStream_t stream) {
  const float* spatial = (const float*)d_in[0];
  const float* met     = (const float*)d_in[1];
  const float* ctx     = (const float*)d_in[2];
  const float* W_ih    = (const float*)d_in[3];
  const float* W_hh    = (const float*)d_in[4];
  const float* b_ih    = (const float*)d_in[5];
  const float* b_hh    = (const float*)d_in[6];
  const float* Wout    = (const float*)d_in[7];
  float* out = (float*)d_out;

  gru_fused<<<dim3(NPIX / 16 / 4), dim3(256), 0, stream>>>(
      spatial, met, ctx, W_ih, W_hh, b_ih, b_hh, Wout, out);
}

// Round 4
// 279.365 us; speedup vs baseline: 1.0140x; 1.0140x over previous
//
#include <hip/hip_runtime.h>
#include <hip/hip_bf16.h>

// GRU fused kernel for MI355X (gfx950). R4 = R3 with compile fix (memcpy
// instead of bit_cast for __hip_bfloat162, which isn't trivially copyable).
// All weights block-staged in padded LDS, hardware bf16 packing
// (v_cvt_pk_bf16_f32), unroll-2 t-loop.
// T=24, N=65536 pixels, F=H=32, gates r,z,n (3H=96).
// One wave = 16 pixels, all 24 steps; gates^T(96x16) = W(96x32) @ x^T/h^T(32x16).

#define TSTEPS 24
#define NPIX 65536
#define PADW 40   // shorts per weight row in LDS (80 B) — breaks bank aliasing

typedef __attribute__((ext_vector_type(8))) short bf16x8;
typedef __attribute__((ext_vector_type(4))) float f32x4;
typedef __attribute__((ext_vector_type(4))) unsigned int u32x4;

#define MFMA16(a, b, c) __builtin_amdgcn_mfma_f32_16x16x32_bf16((a), (b), (c), 0, 0, 0)

__device__ __forceinline__ unsigned short f2bf(float f) {
  unsigned u = __builtin_bit_cast(unsigned, f);
  u += 0x7fffu + ((u >> 16) & 1u);   // RNE (used only in one-time staging)
  return (unsigned short)(u >> 16);
}

// pack two f32 -> dword (bf16(a) low | bf16(b) high) via HW v_cvt_pk_bf16_f32
__device__ __forceinline__ unsigned pk2(float a, float b) {
  __hip_bfloat162 h = __float22bfloat162_rn(float2{a, b});
  unsigned u;
  __builtin_memcpy(&u, &h, sizeof(u));
  return u;
}

__device__ __forceinline__ bf16x8 pack8(f32x4 a, f32x4 b) {
  u32x4 r = { pk2(a[0], a[1]), pk2(a[2], a[3]), pk2(b[0], b[1]), pk2(b[2], b[3]) };
  return __builtin_bit_cast(bf16x8, r);
}

__device__ __forceinline__ float sigmoid_(float x) {
  return __builtin_amdgcn_rcpf(1.f + __expf(-x));
}
__device__ __forceinline__ float tanh_(float x) {
  return 1.f - 2.f * __builtin_amdgcn_rcpf(__expf(2.f * x) + 1.f);
}

// h (two C-layout f32x4 tiles) -> B-layout bf16x8 fragment:
// pack row-pairs into dwords, 8 shuffles + 4 selects.
__device__ __forceinline__ bf16x8 relayout_h(const f32x4 h0, const f32x4 h1, int lane) {
  unsigned p00 = pk2(h0[0], h0[1]), p01 = pk2(h0[2], h0[3]);
  unsigned p10 = pk2(h1[0], h1[1]), p11 = pk2(h1[2], h1[3]);
  const int lo = (lane & 15) | ((lane & 16) << 1);   // col + (q&1)*32
  const int hi = lo + 16;
  unsigned a0 = (unsigned)__shfl((int)p00, lo, 64);
  unsigned a1 = (unsigned)__shfl((int)p01, lo, 64);
  unsigned a2 = (unsigned)__shfl((int)p00, hi, 64);
  unsigned a3 = (unsigned)__shfl((int)p01, hi, 64);
  unsigned b0 = (unsigned)__shfl((int)p10, lo, 64);
  unsigned b1 = (unsigned)__shfl((int)p11, lo, 64);
  unsigned b2 = (unsigned)__shfl((int)p10, hi, 64);
  unsigned b3 = (unsigned)__shfl((int)p11, hi, 64);
  const bool t1 = (lane & 32) != 0;                  // q >= 2 -> tile 1
  u32x4 d = { t1 ? b0 : a0, t1 ? b1 : a1, t1 ? b2 : a2, t1 ? b3 : a3 };
  return __builtin_bit_cast(bf16x8, d);
}

__global__ __launch_bounds__(256, 4)
void gru_fused(const float* __restrict__ spatial, const float* __restrict__ met,
               const float* __restrict__ ctx,
               const float* __restrict__ W_ih, const float* __restrict__ W_hh,
               const float* __restrict__ b_ih, const float* __restrict__ b_hh,
               const float* __restrict__ Wout, float* __restrict__ out) {
  // rows 0..95 = W_ih, rows 96..191 = W_hh; PADW-short stride
  __shared__ __align__(16) unsigned short sW[192 * PADW];
  __shared__ __align__(16) float sCB[64];   // b_ih+b_hh rows 0..63 (r,z)
  __shared__ __align__(16) float sBIN[32];  // b_ih rows 64..95 (n)
  __shared__ __align__(16) float sBHN[32];  // b_hh rows 64..95 (n)

  const int tid = threadIdx.x;
  for (int i = tid; i < 96 * 32; i += 256) {
    int r = i >> 5, c = i & 31;
    sW[r * PADW + c] = f2bf(W_ih[i]);
    sW[(96 + r) * PADW + c] = f2bf(W_hh[i]);
  }
  if (tid < 64) sCB[tid] = b_ih[tid] + b_hh[tid];
  else if (tid < 96) sBIN[tid - 64] = b_ih[tid];
  else if (tid < 128) sBHN[tid - 96] = b_hh[tid - 32];
  __syncthreads();

  const int lane = tid & 63;
  const int col = lane & 15;     // pixel column
  const int q = lane >> 4;       // k-quad
  const int wave = blockIdx.x * 4 + (tid >> 6);
  const long p = (long)wave * 16 + col;

  // biases resident in VGPRs (read once from LDS)
  f32x4 cS[4];
#pragma unroll
  for (int i = 0; i < 4; ++i) cS[i] = *(const f32x4*)&sCB[i * 16 + q * 4];
  const f32x4 cG4 = *(const f32x4*)&sBIN[q * 4];
  const f32x4 cG5 = *(const f32x4*)&sBIN[16 + q * 4];
  const f32x4 cH4 = *(const f32x4*)&sBHN[q * 4];
  const f32x4 cH5 = *(const f32x4*)&sBHN[16 + q * 4];

  // per-lane x stream: lane provides x^T[k=q*8+j][col]
  const float* xptr;
  long xstride;
  if (q < 2)       { xptr = spatial + p * 16 + q * 8; xstride = (long)NPIX * 16; }
  else if (q == 2) { xptr = met + p * 8;              xstride = (long)NPIX * 8;  }
  else             { xptr = ctx + p * 8;              xstride = (long)NPIX * 8;  }

  bf16x8 bx = pack8(*(const f32x4*)xptr, *(const f32x4*)(xptr + 4));
  xptr += xstride;

  f32x4 h0 = {0.f, 0.f, 0.f, 0.f};
  f32x4 h1 = {0.f, 0.f, 0.f, 0.f};

  const int wb = col * PADW + q * 8;   // W_ih fragment base (shorts)

#pragma unroll 2
  for (int t = 0; t < TSTEPS; ++t) {
    // issue next step's x loads early; pack at end of body
    f32x4 xna, xnb;
    if (t < TSTEPS - 1) {
      xna = *(const f32x4*)xptr;
      xnb = *(const f32x4*)(xptr + 4);
      xptr += xstride;
    }

    bf16x8 bh = relayout_h(h0, h1, lane);

    // W_ih fragments (padded LDS, 16B aligned)
    bf16x8 a0 = *(const bf16x8*)&sW[wb];
    bf16x8 a1 = *(const bf16x8*)&sW[wb + 16 * PADW];
    bf16x8 a2 = *(const bf16x8*)&sW[wb + 32 * PADW];
    bf16x8 a3 = *(const bf16x8*)&sW[wb + 48 * PADW];
    bf16x8 a4 = *(const bf16x8*)&sW[wb + 64 * PADW];
    bf16x8 a5 = *(const bf16x8*)&sW[wb + 80 * PADW];
    // W_hh fragments
    bf16x8 w0 = *(const bf16x8*)&sW[wb + 96 * PADW];
    bf16x8 w1 = *(const bf16x8*)&sW[wb + 112 * PADW];
    bf16x8 w2 = *(const bf16x8*)&sW[wb + 128 * PADW];
    bf16x8 w3 = *(const bf16x8*)&sW[wb + 144 * PADW];
    bf16x8 w4 = *(const bf16x8*)&sW[wb + 160 * PADW];
    bf16x8 w5 = *(const bf16x8*)&sW[wb + 176 * PADW];

    // gx (bias in C), then chain gh onto it for r/z tiles
    f32x4 g0 = MFMA16(a0, bx, cS[0]);
    f32x4 g1 = MFMA16(a1, bx, cS[1]);
    f32x4 g2 = MFMA16(a2, bx, cS[2]);
    f32x4 g3 = MFMA16(a3, bx, cS[3]);
    f32x4 G4 = MFMA16(a4, bx, cG4);
    f32x4 G5 = MFMA16(a5, bx, cG5);
    f32x4 S0 = MFMA16(w0, bh, g0);
    f32x4 S1 = MFMA16(w1, bh, g1);
    f32x4 S2 = MFMA16(w2, bh, g2);
    f32x4 S3 = MFMA16(w3, bh, g3);
    f32x4 H4 = MFMA16(w4, bh, cH4);
    f32x4 H5 = MFMA16(w5, bh, cH5);

    // gate math (S0,S1=r  S2,S3=z  G4/H4,G5/H5=n ; h tiles 0,1)
#pragma unroll
    for (int r = 0; r < 4; ++r) {
      float rv0 = sigmoid_(S0[r]);
      float rv1 = sigmoid_(S1[r]);
      float zv0 = sigmoid_(S2[r]);
      float zv1 = sigmoid_(S3[r]);
      float nv0 = tanh_(G4[r] + rv0 * H4[r]);
      float nv1 = tanh_(G5[r] + rv1 * H5[r]);
      h0[r] = nv0 + zv0 * (h0[r] - nv0);
      h1[r] = nv1 + zv1 * (h1[r] - nv1);
    }

    if (t < TSTEPS - 1) bx = pack8(xna, xnb);
  }

  // epilogue: out^T(16x16) = W^T(16x32) @ h^T(32x16)
  bf16x8 bhf = relayout_h(h0, h1, lane);
  float w[8];
#pragma unroll
  for (int j = 0; j < 8; ++j) w[j] = Wout[(q * 8 + j) * 16 + col];
  u32x4 awp = { pk2(w[0], w[1]), pk2(w[2], w[3]), pk2(w[4], w[5]), pk2(w[6], w[7]) };
  bf16x8 aw = __builtin_bit_cast(bf16x8, awp);
  const f32x4 zero = {0.f, 0.f, 0.f, 0.f};
  f32x4 o = MFMA16(aw, bhf, zero);
  *(f32x4*)&out[p * 16 + q * 4] = o;
}

extern "C" void kernel_launch(void* const* d_in, const int* in_sizes, int n_in,
                              void* d_out, int out_size, void* d_ws, size_t ws_size,
                              hipStream_t stream) {
  const float* spatial = (const float*)d_in[0];
  const float* met     = (const float*)d_in[1];
  const float* ctx     = (const float*)d_in[2];
  const float* W_ih    = (const float*)d_in[3];
  const float* W_hh    = (const float*)d_in[4];
  const float* b_ih    = (const float*)d_in[5];
  const float* b_hh    = (const float*)d_in[6];
  const float* Wout    = (const float*)d_in[7];
  float* out = (float*)d_out;

  gru_fused<<<dim3(NPIX / 16 / 4), dim3(256), 0, stream>>>(
      spatial, met, ctx, W_ih, W_hh, b_ih, b_hh, Wout, out);
}

// Round 5
// 233.076 us; speedup vs baseline: 1.2154x; 1.1986x over previous
//
#include <hip/hip_runtime.h>
#include <hip/hip_bf16.h>

// GRU fused kernel for MI355X (gfx950). R5: R1 dataflow (12 independent MFMAs,
// no C-chaining) + dual pixel-group per wave for 2x ILP on the serial
// recurrence chain + PADW=40 LDS padding + HW bf16 packing.
// T=24, N=65536 pixels, F=H=32, gates r,z,n (3H=96).
// One wave = 32 pixels (2 groups of 16), all 24 steps.
// gates^T(96x16) = W(96x32) @ x^T/h^T(32x16) per group; weight frags shared.

#define TSTEPS 24
#define NPIX 65536
#define PADW 40   // shorts per weight row in LDS (80 B) — breaks bank aliasing

typedef __attribute__((ext_vector_type(8))) short bf16x8;
typedef __attribute__((ext_vector_type(4))) float f32x4;
typedef __attribute__((ext_vector_type(4))) unsigned int u32x4;

#define MFMA16(a, b, c) __builtin_amdgcn_mfma_f32_16x16x32_bf16((a), (b), (c), 0, 0, 0)

__device__ __forceinline__ unsigned short f2bf(float f) {
  unsigned u = __builtin_bit_cast(unsigned, f);
  u += 0x7fffu + ((u >> 16) & 1u);   // RNE (one-time staging only)
  return (unsigned short)(u >> 16);
}

// pack two f32 -> dword (bf16(a) low | bf16(b) high) via HW v_cvt_pk_bf16_f32
__device__ __forceinline__ unsigned pk2(float a, float b) {
  __hip_bfloat162 h = __float22bfloat162_rn(float2{a, b});
  unsigned u;
  __builtin_memcpy(&u, &h, sizeof(u));
  return u;
}

__device__ __forceinline__ bf16x8 pack8(f32x4 a, f32x4 b) {
  u32x4 r = { pk2(a[0], a[1]), pk2(a[2], a[3]), pk2(b[0], b[1]), pk2(b[2], b[3]) };
  return __builtin_bit_cast(bf16x8, r);
}

__device__ __forceinline__ float sigmoid_(float x) {
  return __builtin_amdgcn_rcpf(1.f + __expf(-x));
}
__device__ __forceinline__ float tanh_(float x) {
  return 1.f - 2.f * __builtin_amdgcn_rcpf(__expf(2.f * x) + 1.f);
}

// h (two C-layout f32x4 tiles) -> B-layout bf16x8 fragment:
// pack row-pairs into dwords, 8 shuffles + 4 selects.
__device__ __forceinline__ bf16x8 relayout_h(const f32x4 h0, const f32x4 h1, int lane) {
  unsigned p00 = pk2(h0[0], h0[1]), p01 = pk2(h0[2], h0[3]);
  unsigned p10 = pk2(h1[0], h1[1]), p11 = pk2(h1[2], h1[3]);
  const int lo = (lane & 15) | ((lane & 16) << 1);   // col + (q&1)*32
  const int hi = lo + 16;
  unsigned a0 = (unsigned)__shfl((int)p00, lo, 64);
  unsigned a1 = (unsigned)__shfl((int)p01, lo, 64);
  unsigned a2 = (unsigned)__shfl((int)p00, hi, 64);
  unsigned a3 = (unsigned)__shfl((int)p01, hi, 64);
  unsigned b0 = (unsigned)__shfl((int)p10, lo, 64);
  unsigned b1 = (unsigned)__shfl((int)p11, lo, 64);
  unsigned b2 = (unsigned)__shfl((int)p10, hi, 64);
  unsigned b3 = (unsigned)__shfl((int)p11, hi, 64);
  const bool t1 = (lane & 32) != 0;                  // q >= 2 -> tile 1
  u32x4 d = { t1 ? b0 : a0, t1 ? b1 : a1, t1 ? b2 : a2, t1 ? b3 : a3 };
  return __builtin_bit_cast(bf16x8, d);
}

__global__ __launch_bounds__(256, 2)
void gru_fused(const float* __restrict__ spatial, const float* __restrict__ met,
               const float* __restrict__ ctx,
               const float* __restrict__ W_ih, const float* __restrict__ W_hh,
               const float* __restrict__ b_ih, const float* __restrict__ b_hh,
               const float* __restrict__ Wout, float* __restrict__ out) {
  // rows 0..95 = W_ih, rows 96..191 = W_hh; PADW-short stride
  __shared__ __align__(16) unsigned short sW[192 * PADW];
  __shared__ __align__(16) float sCB[64];   // b_ih+b_hh rows 0..63 (r,z)
  __shared__ __align__(16) float sBIN[32];  // b_ih rows 64..95 (n)
  __shared__ __align__(16) float sBHN[32];  // b_hh rows 64..95 (n)

  const int tid = threadIdx.x;
  for (int i = tid; i < 96 * 32; i += 256) {
    int r = i >> 5, c = i & 31;
    sW[r * PADW + c] = f2bf(W_ih[i]);
    sW[(96 + r) * PADW + c] = f2bf(W_hh[i]);
  }
  if (tid < 64) sCB[tid] = b_ih[tid] + b_hh[tid];
  else if (tid < 96) sBIN[tid - 64] = b_ih[tid];
  else if (tid < 128) sBHN[tid - 96] = b_hh[tid - 32];
  __syncthreads();

  const int lane = tid & 63;
  const int col = lane & 15;     // pixel column within group
  const int q = lane >> 4;       // k-quad
  const int wave = blockIdx.x * 4 + (tid >> 6);
  const long p0 = (long)wave * 32 + col;   // group 0 pixel
  const long p1 = p0 + 16;                 // group 1 pixel

  // biases resident (read once from LDS)
  f32x4 cS[4];
#pragma unroll
  for (int i = 0; i < 4; ++i) cS[i] = *(const f32x4*)&sCB[i * 16 + q * 4];
  const f32x4 cG4 = *(const f32x4*)&sBIN[q * 4];
  const f32x4 cG5 = *(const f32x4*)&sBIN[16 + q * 4];
  const f32x4 cH4 = *(const f32x4*)&sBHN[q * 4];
  const f32x4 cH5 = *(const f32x4*)&sBHN[16 + q * 4];

  // per-lane x streams (lane provides x^T[k=q*8+j][col] for each group)
  const float *xp0, *xp1;
  long xstride;
  if (q < 2) {
    xp0 = spatial + p0 * 16 + q * 8; xp1 = spatial + p1 * 16 + q * 8;
    xstride = (long)NPIX * 16;
  } else if (q == 2) {
    xp0 = met + p0 * 8; xp1 = met + p1 * 8; xstride = (long)NPIX * 8;
  } else {
    xp0 = ctx + p0 * 8; xp1 = ctx + p1 * 8; xstride = (long)NPIX * 8;
  }

  bf16x8 bx0 = pack8(*(const f32x4*)xp0, *(const f32x4*)(xp0 + 4));
  bf16x8 bx1 = pack8(*(const f32x4*)xp1, *(const f32x4*)(xp1 + 4));
  xp0 += xstride; xp1 += xstride;

  f32x4 h0a = {0.f, 0.f, 0.f, 0.f}, h0b = {0.f, 0.f, 0.f, 0.f};   // group 0
  f32x4 h1a = {0.f, 0.f, 0.f, 0.f}, h1b = {0.f, 0.f, 0.f, 0.f};   // group 1
  const f32x4 zero = {0.f, 0.f, 0.f, 0.f};

  const int wb = col * PADW + q * 8;   // fragment base (shorts)

#pragma unroll 1
  for (int t = 0; t < TSTEPS; ++t) {
    // issue next step's x loads early (4 independent b128 loads)
    f32x4 xn0a, xn0b, xn1a, xn1b;
    if (t < TSTEPS - 1) {
      xn0a = *(const f32x4*)xp0; xn0b = *(const f32x4*)(xp0 + 4);
      xn1a = *(const f32x4*)xp1; xn1b = *(const f32x4*)(xp1 + 4);
      xp0 += xstride; xp1 += xstride;
    }

    // both groups' h -> B-layout (independent shuffle batches)
    bf16x8 bh0 = relayout_h(h0a, h0b, lane);
    bf16x8 bh1 = relayout_h(h1a, h1b, lane);

    // weight fragments (padded LDS, shared by both groups)
    bf16x8 a0 = *(const bf16x8*)&sW[wb];
    bf16x8 a1 = *(const bf16x8*)&sW[wb + 16 * PADW];
    bf16x8 a2 = *(const bf16x8*)&sW[wb + 32 * PADW];
    bf16x8 a3 = *(const bf16x8*)&sW[wb + 48 * PADW];
    bf16x8 a4 = *(const bf16x8*)&sW[wb + 64 * PADW];
    bf16x8 a5 = *(const bf16x8*)&sW[wb + 80 * PADW];
    bf16x8 w0 = *(const bf16x8*)&sW[wb + 96 * PADW];
    bf16x8 w1 = *(const bf16x8*)&sW[wb + 112 * PADW];
    bf16x8 w2 = *(const bf16x8*)&sW[wb + 128 * PADW];
    bf16x8 w3 = *(const bf16x8*)&sW[wb + 144 * PADW];
    bf16x8 w4 = *(const bf16x8*)&sW[wb + 160 * PADW];
    bf16x8 w5 = *(const bf16x8*)&sW[wb + 176 * PADW];

    // 24 independent MFMAs (12 per group), biases folded into C-init
    f32x4 G0[6], H0[6], G1[6], H1[6];
    G0[0] = MFMA16(a0, bx0, cS[0]);  G1[0] = MFMA16(a0, bx1, cS[0]);
    G0[1] = MFMA16(a1, bx0, cS[1]);  G1[1] = MFMA16(a1, bx1, cS[1]);
    G0[2] = MFMA16(a2, bx0, cS[2]);  G1[2] = MFMA16(a2, bx1, cS[2]);
    G0[3] = MFMA16(a3, bx0, cS[3]);  G1[3] = MFMA16(a3, bx1, cS[3]);
    G0[4] = MFMA16(a4, bx0, cG4);    G1[4] = MFMA16(a4, bx1, cG4);
    G0[5] = MFMA16(a5, bx0, cG5);    G1[5] = MFMA16(a5, bx1, cG5);
    H0[0] = MFMA16(w0, bh0, zero);   H1[0] = MFMA16(w0, bh1, zero);
    H0[1] = MFMA16(w1, bh0, zero);   H1[1] = MFMA16(w1, bh1, zero);
    H0[2] = MFMA16(w2, bh0, zero);   H1[2] = MFMA16(w2, bh1, zero);
    H0[3] = MFMA16(w3, bh0, zero);   H1[3] = MFMA16(w3, bh1, zero);
    H0[4] = MFMA16(w4, bh0, cH4);    H1[4] = MFMA16(w4, bh1, cH4);
    H0[5] = MFMA16(w5, bh0, cH5);    H1[5] = MFMA16(w5, bh1, cH5);

    // gate math for both groups (independent chains)
#pragma unroll
    for (int r = 0; r < 4; ++r) {
      float r00 = sigmoid_(G0[0][r] + H0[0][r]);
      float r01 = sigmoid_(G0[1][r] + H0[1][r]);
      float z00 = sigmoid_(G0[2][r] + H0[2][r]);
      float z01 = sigmoid_(G0[3][r] + H0[3][r]);
      float n00 = tanh_(G0[4][r] + r00 * H0[4][r]);
      float n01 = tanh_(G0[5][r] + r01 * H0[5][r]);
      h0a[r] = n00 + z00 * (h0a[r] - n00);
      h0b[r] = n01 + z01 * (h0b[r] - n01);

      float r10 = sigmoid_(G1[0][r] + H1[0][r]);
      float r11 = sigmoid_(G1[1][r] + H1[1][r]);
      float z10 = sigmoid_(G1[2][r] + H1[2][r]);
      float z11 = sigmoid_(G1[3][r] + H1[3][r]);
      float n10 = tanh_(G1[4][r] + r10 * H1[4][r]);
      float n11 = tanh_(G1[5][r] + r11 * H1[5][r]);
      h1a[r] = n10 + z10 * (h1a[r] - n10);
      h1b[r] = n11 + z11 * (h1b[r] - n11);
    }

    if (t < TSTEPS - 1) {
      bx0 = pack8(xn0a, xn0b);
      bx1 = pack8(xn1a, xn1b);
    }
  }

  // epilogue: out^T(16x16) = W^T(16x32) @ h^T(32x16) per group
  bf16x8 bhf0 = relayout_h(h0a, h0b, lane);
  bf16x8 bhf1 = relayout_h(h1a, h1b, lane);
  float w[8];
#pragma unroll
  for (int j = 0; j < 8; ++j) w[j] = Wout[(q * 8 + j) * 16 + col];
  u32x4 awp = { pk2(w[0], w[1]), pk2(w[2], w[3]), pk2(w[4], w[5]), pk2(w[6], w[7]) };
  bf16x8 aw = __builtin_bit_cast(bf16x8, awp);
  f32x4 o0 = MFMA16(aw, bhf0, zero);
  f32x4 o1 = MFMA16(aw, bhf1, zero);
  *(f32x4*)&out[p0 * 16 + q * 4] = o0;
  *(f32x4*)&out[p1 * 16 + q * 4] = o1;
}

extern "C" void kernel_launch(void* const* d_in, const int* in_sizes, int n_in,
                              void* d_out, int out_size, void* d_ws, size_t ws_size,
                              hipStream_t stream) {
  const float* spatial = (const float*)d_in[0];
  const float* met     = (const float*)d_in[1];
  const float* ctx     = (const float*)d_in[2];
  const float* W_ih    = (const float*)d_in[3];
  const float* W_hh    = (const float*)d_in[4];
  const float* b_ih    = (const float*)d_in[5];
  const float* b_hh    = (const float*)d_in[6];
  const float* Wout    = (const float*)d_in[7];
  float* out = (float*)d_out;

  // 2048 waves x 32 px; 512 blocks of 256 = 2 blocks/CU, 8 waves/CU
  gru_fused<<<dim3(NPIX / 32 / 4), dim3(256), 0, stream>>>(
      spatial, met, ctx, W_ih, W_hh, b_ih, b_hh, Wout, out);
}